// Round 9
// baseline (180.823 us; speedup 1.0000x reference)
//
#include <hip/hip_runtime.h>

// Problem constants: B=4, S=4096, D=1024, H=64
#define NS 8       // attention key-range splits

typedef __attribute__((ext_vector_type(8))) short sh8;  // 8 x bf16 (4 VGPRs)
typedef __attribute__((ext_vector_type(4))) short sh4;  // 4 x bf16 (8 B)
typedef __attribute__((ext_vector_type(4))) float f4;   // MFMA accumulator

// fold 1/sqrt(64) * log2(e) into Q so softmax is pure exp2
#define QSCALE 0.18033688011112042f

typedef const __attribute__((address_space(1))) unsigned int* gas_t;
typedef __attribute__((address_space(3))) unsigned int* las_t;
#define GLD16(g, l) __builtin_amdgcn_global_load_lds((gas_t)(g), (las_t)(l), 16, 0, 0)

static __device__ __forceinline__ unsigned short f2bf(float f) {
  unsigned u = __builtin_bit_cast(unsigned, f);
  u += 0x7fffu + ((u >> 16) & 1u);   // RNE
  return (unsigned short)(u >> 16);
}
static __device__ __forceinline__ float bf2f(unsigned short s) {
  unsigned u = ((unsigned)s) << 16;
  return __builtin_bit_cast(float, u);
}

// ---------------- kernel 1: Wt[192][1024] bf16 = concat(Wq,Wk,Wv)^T ----------------
__global__ __launch_bounds__(256) void wt_kernel(const float* __restrict__ Wq,
                                                 const float* __restrict__ Wk,
                                                 const float* __restrict__ Wv,
                                                 unsigned short* __restrict__ Wt) {
  __shared__ float tile[64 * 65];
  int widx = blockIdx.x >> 4, kt = blockIdx.x & 15;
  const float* W = widx == 0 ? Wq : (widx == 1 ? Wk : Wv);
  int t = threadIdx.x;
  {
    int kl = t >> 2, seg = (t & 3) * 16;
    const float* src = W + (size_t)(kt * 64 + kl) * 64 + seg;
#pragma unroll
    for (int j = 0; j < 16; ++j) tile[kl * 65 + seg + j] = src[j];
  }
  __syncthreads();
  {
    int nl = t >> 2, ks = (t & 3) * 16;
    unsigned short* dst = Wt + (size_t)(widx * 64 + nl) * 1024 + kt * 64 + ks;
#pragma unroll
    for (int j = 0; j < 16; ++j) dst[j] = f2bf(tile[(ks + j) * 65 + nl]);
  }
}

// ---------------- kernel 2: projection, glds pipeline, k-split x2 ----------------
// Grid 1024 = 512 m-tiles (M=32) x 2 k-halves (K=512, 16 iters). 4 blocks/CU.
// Same per-iteration staging/MFMA as the 512-block version; half the pipeline length,
// double the resident blocks to overlap barrier drains. bf16 partials to Pp.
__global__ __launch_bounds__(256, 4) void proj_kernel(const float* __restrict__ in,
                                                      const unsigned short* __restrict__ Wt,
                                                      unsigned short* __restrict__ Pp) {
  __shared__ __align__(16) char lds[32768];
  int t = threadIdx.x;
  int w = t >> 6, lane = t & 63, q = lane >> 4, l15 = lane & 15;
  int m0 = (blockIdx.x >> 1) * 32;
  int ksp = blockIdx.x & 1;
  int kbase = ksp * 512;

  int mt_s = w >> 1, i_s = w & 1;
  const float* ga = in + (size_t)(m0 + mt_s * 16 + l15) * 1024 + kbase + q * 8 + i_s * 4;
  const unsigned short* gb = Wt + (size_t)(w * 48 + l15) * 1024 + kbase + q * 8;

  f4 acc[2][3];
  f4 z = {0.f, 0.f, 0.f, 0.f};
#pragma unroll
  for (int mt = 0; mt < 2; ++mt)
#pragma unroll
    for (int nt = 0; nt < 3; ++nt) acc[mt][nt] = z;

#define STAGE(kt, buf)                                                        \
  {                                                                           \
    int k0 = (kt) * 32;                                                       \
    char* base = lds + (buf) * 16384;                                         \
    GLD16(ga + k0, base + w * 1024);                                          \
    GLD16(gb + k0, base + 4096 + (w * 3 + 0) * 1024);                         \
    GLD16(gb + 16384 + k0, base + 4096 + (w * 3 + 1) * 1024);                 \
    GLD16(gb + 32768 + k0, base + 4096 + (w * 3 + 2) * 1024);                 \
  }

  STAGE(0, 0);
  for (int kt = 0; kt < 16; ++kt) {
    int cur = kt & 1;
    __syncthreads();
    if (kt + 1 < 16) STAGE(kt + 1, cur ^ 1);

    const f4* Af = (const f4*)(lds + cur * 16384);
    f4 lo0 = Af[0 * 64 + lane], hi0 = Af[1 * 64 + lane];
    f4 lo1 = Af[2 * 64 + lane], hi1 = Af[3 * 64 + lane];
    sh8 a0, a1;
#pragma unroll
    for (int j = 0; j < 4; ++j) {
      a0[j] = (short)f2bf(lo0[j]); a0[4 + j] = (short)f2bf(hi0[j]);
      a1[j] = (short)f2bf(lo1[j]); a1[4 + j] = (short)f2bf(hi1[j]);
    }
    const sh8* Bf = (const sh8*)(lds + cur * 16384 + 4096);
#pragma unroll
    for (int nt = 0; nt < 3; ++nt) {
      sh8 bf = Bf[(w * 3 + nt) * 64 + lane];
      acc[0][nt] = __builtin_amdgcn_mfma_f32_16x16x32_bf16(a0, bf, acc[0][nt], 0, 0, 0);
      acc[1][nt] = __builtin_amdgcn_mfma_f32_16x16x32_bf16(a1, bf, acc[1][nt], 0, 0, 0);
    }
  }
#undef STAGE

  // epilogue: direct bf16 partial stores (C-layout row = mt*16 + q*4 + r, col = band*16+l15)
#pragma unroll
  for (int nt = 0; nt < 3; ++nt) {
    int band = w * 3 + nt;
#pragma unroll
    for (int mt = 0; mt < 2; ++mt)
#pragma unroll
      for (int r = 0; r < 4; ++r) {
        int row = mt * 16 + q * 4 + r;
        Pp[((size_t)ksp * 16384 + m0 + row) * 192 + band * 16 + l15] = f2bf(acc[mt][nt][r]);
      }
  }
}

// ---------------- kernel 3: combine k-split partials -> Qg (scaled), Kg, Vtg ----------------
__global__ __launch_bounds__(256) void proj_combine(const unsigned short* __restrict__ Pp,
                                                    unsigned short* __restrict__ Qg,
                                                    unsigned short* __restrict__ Kg,
                                                    unsigned short* __restrict__ Vtg) {
  __shared__ unsigned short vtile[64 * 72];
  int t = threadIdx.x;
  int m0 = blockIdx.x * 64;
  int row = t >> 2, cg = t & 3;   // 64 rows x 4 col-groups of 48
  {
    const sh8* p0 = (const sh8*)(Pp + (size_t)(m0 + row) * 192 + cg * 48);
    const sh8* p1 = (const sh8*)(Pp + ((size_t)16384 + m0 + row) * 192 + cg * 48);
    sh8 a0[6], a1[6];
#pragma unroll
    for (int i = 0; i < 6; ++i) { a0[i] = p0[i]; a1[i] = p1[i]; }
#pragma unroll
    for (int i = 0; i < 6; ++i)
#pragma unroll
      for (int j = 0; j < 8; ++j) {
        int c = cg * 48 + i * 8 + j;
        float v = bf2f((unsigned short)a0[i][j]) + bf2f((unsigned short)a1[i][j]);
        if (c < 64)       Qg[(size_t)(m0 + row) * 64 + c] = f2bf(v * QSCALE);
        else if (c < 128) Kg[(size_t)(m0 + row) * 64 + (c - 64)] = f2bf(v);
        else              vtile[row * 72 + (c - 128)] = f2bf(v);
      }
  }
  __syncthreads();
  {
    int h = t >> 2, ss = (t & 3) * 16;
    int bb = m0 >> 12, s0 = m0 & 4095;
    unsigned short tmp[16];
#pragma unroll
    for (int j = 0; j < 16; ++j) tmp[j] = vtile[(ss + j) * 72 + h];
    unsigned short* dst = Vtg + (((size_t)(bb * 64 + h)) << 12) + s0 + ss;
    *(sh8*)dst = *(sh8*)tmp;
    *(sh8*)(dst + 8) = *(sh8*)(tmp + 8);
  }
}

// ---------------- kernel 4: causal flash attention, q-tile 128, S^T trick, split-K ----------------
// grid (32*NS, B), 256 threads (4 waves). Wave = two 16-row q-subtiles (+0, +64) sharing
// each staged 64-key K/V tile: double MFMA per barrier, half the block-iterations.
__global__ __launch_bounds__(256, 4) void attn_split(const unsigned short* __restrict__ Qg,
                                                     const unsigned short* __restrict__ Kg,
                                                     const unsigned short* __restrict__ Vtg,
                                                     unsigned short* __restrict__ Opart,
                                                     float* __restrict__ Lpart) {
  __shared__ unsigned short Ks[64 * 72];
  __shared__ unsigned short Vs[64 * 72];
  __shared__ unsigned short Pw[4 * 16 * 72];
  int t = threadIdx.x;
  int b = blockIdx.y;
  int qt = 31 - (int)(blockIdx.x >> 3);  // heavy q-tiles first (LPT)
  int sp = blockIdx.x & 7;
  int wave = t >> 6, lane = t & 63, quad = lane >> 4, l15 = lane & 15;
  unsigned short* Pws = Pw + wave * 16 * 72;

  int qrow0[2] = {qt * 128 + wave * 16, qt * 128 + 64 + wave * 16};
  size_t pbase = ((size_t)sp * 4 + b) * 4096;

  int nkt = 2 * qt + 2;
  int chunk = (nkt + NS - 1) / NS;
  int t0 = sp * chunk, t1 = min(nkt, t0 + chunk);
  if (t0 >= t1) {  // empty chunk: zero partials for both subtiles
#pragma unroll
    for (int s = 0; s < 2; ++s)
#pragma unroll
      for (int r = 0; r < 4; ++r) {
        size_t row = pbase + qrow0[s] + quad * 4 + r;
#pragma unroll
        for (int ht = 0; ht < 4; ++ht) Opart[row * 64 + ht * 16 + l15] = 0;
        if (l15 == 0) Lpart[row] = 0.f;
      }
    return;
  }

  sh8 qa[2][2];
#pragma unroll
  for (int s = 0; s < 2; ++s)
#pragma unroll
    for (int ks = 0; ks < 2; ++ks)
      qa[s][ks] = *(const sh8*)&Qg[(size_t)((b << 12) + qrow0[s] + l15) * 64 + ks * 32 + quad * 8];

  sh8 ones;
#pragma unroll
  for (int j = 0; j < 8; ++j) ones[j] = (short)0x3F80;  // bf16 1.0

  f4 o[2][5];  // per subtile: o[0..3] O accumulator; o[4] row-sum (P * ones)
  f4 z = {0.f, 0.f, 0.f, 0.f};
#pragma unroll
  for (int s = 0; s < 2; ++s)
#pragma unroll
    for (int ht = 0; ht < 5; ++ht) o[s][ht] = z;

  // staging geometry: thread covers chunks c0=t, c1=t+256; row=c>>3, off=(c&7)*8
  int r0 = t >> 3, o0 = (t & 7) * 8;
  int r1 = (t + 256) >> 3, o1 = ((t + 256) & 7) * 8;
  const unsigned short* kg0 = Kg + (size_t)((b << 12) + r0) * 64 + o0;
  const unsigned short* kg1 = Kg + (size_t)((b << 12) + r1) * 64 + o1;
  const unsigned short* vg0 = Vtg + (((size_t)(b * 64 + r0)) << 12) + o0;
  const unsigned short* vg1 = Vtg + (((size_t)(b * 64 + r1)) << 12) + o1;

  sh8 kr0, kr1, vr0, vr1;
  {
    size_t ko = (size_t)t0 * 64 * 64;
    kr0 = *(const sh8*)(kg0 + ko); kr1 = *(const sh8*)(kg1 + ko);
    vr0 = *(const sh8*)(vg0 + t0 * 64); vr1 = *(const sh8*)(vg1 + t0 * 64);
  }

  for (int kt = t0; kt < t1; ++kt) {
    __syncthreads();                      // prev-iter LDS reads done
    *(sh8*)&Ks[r0 * 72 + o0] = kr0;
    *(sh8*)&Ks[r1 * 72 + o1] = kr1;
    *(sh8*)&Vs[r0 * 72 + o0] = vr0;
    *(sh8*)&Vs[r1 * 72 + o1] = vr1;
    if (kt + 1 < t1) {                    // prefetch next tile into regs
      size_t ko = (size_t)(kt + 1) * 64 * 64;
      kr0 = *(const sh8*)(kg0 + ko); kr1 = *(const sh8*)(kg1 + ko);
      vr0 = *(const sh8*)(vg0 + (kt + 1) * 64); vr1 = *(const sh8*)(vg1 + (kt + 1) * 64);
    }
    __syncthreads();                      // Ks/Vs visible

#pragma unroll
    for (int s = 0; s < 2; ++s) {
      if (kt > 2 * qt + s) continue;      // fully-masked subtile (block-uniform)

      // S^T = K * Q_s^T: lane(quad,l15) reg r = S[qrow0+l15][kt*64+nt*16+quad*4+r]
      f4 st[4];
#pragma unroll
      for (int nt = 0; nt < 4; ++nt) st[nt] = z;
#pragma unroll
      for (int ks = 0; ks < 2; ++ks) {
#pragma unroll
        for (int nt = 0; nt < 4; ++nt) {
          sh8 kb = *(const sh8*)&Ks[(nt * 16 + l15) * 72 + ks * 32 + quad * 8];
          st[nt] = __builtin_amdgcn_mfma_f32_16x16x32_bf16(kb, qa[s][ks], st[nt], 0, 0, 0);
        }
      }

      if (kt == 2 * qt + s) {  // diagonal tile for this subtile
        int qrow = qrow0[s] + l15;
#pragma unroll
        for (int nt = 0; nt < 4; ++nt) {
          int key0 = kt * 64 + nt * 16 + quad * 4;
#pragma unroll
          for (int r = 0; r < 4; ++r)
            if (key0 + r > qrow) st[nt][r] = -__builtin_inff();
        }
      }

      // static-max softmax: P = exp2(S); 4 contiguous keys -> one b64 LDS write
#pragma unroll
      for (int nt = 0; nt < 4; ++nt) {
        sh4 pk;
#pragma unroll
        for (int r = 0; r < 4; ++r) pk[r] = (short)f2bf(exp2f(st[nt][r]));
        *(sh4*)&Pws[l15 * 72 + nt * 16 + quad * 4] = pk;
      }
      asm volatile("s_waitcnt lgkmcnt(0)" ::: "memory");

#pragma unroll
      for (int ks = 0; ks < 2; ++ks) {
        sh8 pa = *(const sh8*)&Pws[l15 * 72 + ks * 32 + quad * 8];
#pragma unroll
        for (int ht = 0; ht < 4; ++ht) {
          sh8 vb = *(const sh8*)&Vs[(ht * 16 + l15) * 72 + ks * 32 + quad * 8];
          o[s][ht] = __builtin_amdgcn_mfma_f32_16x16x32_bf16(pa, vb, o[s][ht], 0, 0, 0);
        }
        o[s][4] = __builtin_amdgcn_mfma_f32_16x16x32_bf16(pa, ones, o[s][4], 0, 0, 0);
      }
    }
  }

  // write partials (unnormalized O, bf16; L fp32)
#pragma unroll
  for (int s = 0; s < 2; ++s)
#pragma unroll
    for (int r = 0; r < 4; ++r) {
      size_t row = pbase + qrow0[s] + quad * 4 + r;
#pragma unroll
      for (int ht = 0; ht < 4; ++ht)
        Opart[row * 64 + ht * 16 + l15] = f2bf(o[s][ht][r]);
      if (l15 == 0) Lpart[row] = o[s][4][r];
    }
}

// ---------------- kernel 5: combine split partials ----------------
__global__ __launch_bounds__(256) void attn_combine(const unsigned short* __restrict__ Opart,
                                                    const float* __restrict__ Lpart,
                                                    float* __restrict__ out) {
  int t = threadIdx.x;
  int rg = blockIdx.x * 4 + (t >> 6);  // global row 0..16383
  int lane = t & 63;
  float acc = 0.f, L = 0.f;
#pragma unroll
  for (int s = 0; s < NS; ++s) {
    L += Lpart[(size_t)s * 16384 + rg];
    acc += bf2f(Opart[((size_t)s * 16384 + rg) * 64 + lane]);
  }
  out[(size_t)rg * 64 + lane] = acc / L;
}

extern "C" void kernel_launch(void* const* d_in, const int* in_sizes, int n_in,
                              void* d_out, int out_size, void* d_ws, size_t ws_size,
                              hipStream_t stream) {
  const float* in = (const float*)d_in[0];
  const float* Wq = (const float*)d_in[1];
  const float* Wk = (const float*)d_in[2];
  const float* Wv = (const float*)d_in[3];
  float* out = (float*)d_out;

  char* ws = (char*)d_ws;
  unsigned short* Wt    = (unsigned short*)ws;                 // 393,216 B
  unsigned short* Pp    = (unsigned short*)(ws + 393216);      // 12,582,912 B
  unsigned short* Qg    = (unsigned short*)(ws + 12976128);    // 2 MiB
  unsigned short* Kg    = (unsigned short*)(ws + 15073280);    // 2 MiB
  unsigned short* Vtg   = (unsigned short*)(ws + 17170432);    // 2 MiB
  unsigned short* Opart = (unsigned short*)(ws + 19267584);    // 16,777,216 B
  float*          Lpart = (float*)(ws + 36044800);             // 524,288 B
  // total ws use ~36.6 MiB

  hipLaunchKernelGGL(wt_kernel, dim3(48), dim3(256), 0, stream, Wq, Wk, Wv, Wt);
  hipLaunchKernelGGL(proj_kernel, dim3(1024), dim3(256), 0, stream, in, Wt, Pp);
  hipLaunchKernelGGL(proj_combine, dim3(256), dim3(256), 0, stream, Pp, Qg, Kg, Vtg);
  hipLaunchKernelGGL(attn_split, dim3(32 * NS, 4), dim3(256), 0, stream,
                     Qg, Kg, Vtg, Opart, Lpart);
  hipLaunchKernelGGL(attn_combine, dim3(4096), dim3(256), 0, stream,
                     Opart, Lpart, out);
}